// Round 1
// baseline (9464.464 us; speedup 1.0000x reference)
//
#include <hip/hip_runtime.h>

// ---------------------------------------------------------------------------
// Sizes (fixed by the problem): B=8, C=dm=256, H=W=64, N=H*W=4096
// ws layout: q_t[8][4096][256] | k_t[...] | v_t[...] | scale[256] | shift[256]
// d_out: y = r + xc (NCHW fp32), normalized in place by BN kernels.
// ---------------------------------------------------------------------------

// ---------------- Kernel A: 1x1 conv + bias + relu -> q_t [b][n][c] --------
__global__ __launch_bounds__(256) void k_conv1x1(
    const float* __restrict__ x, const float* __restrict__ wq,
    const float* __restrict__ bq, float* __restrict__ q_t)
{
  __shared__ float xs[8 * 256];
  const int tid = threadIdx.x;
  const int n0  = blockIdx.x * 256;
  const int co0 = blockIdx.y * 32;
  const int b   = blockIdx.z;

  float acc[32];
#pragma unroll
  for (int i = 0; i < 32; ++i) acc[i] = 0.f;

  const float* xb = x + (size_t)b * 256 * 4096;
  for (int ci0 = 0; ci0 < 256; ci0 += 8) {
    __syncthreads();
    for (int i = tid; i < 8 * 256; i += 256) {
      int c = i >> 8, sp = i & 255;
      xs[i] = xb[(size_t)(ci0 + c) * 4096 + n0 + sp];
    }
    __syncthreads();
#pragma unroll 2
    for (int c = 0; c < 8; ++c) {
      float xv = xs[c * 256 + tid];
      const float* wrow = wq + (size_t)co0 * 256 + (ci0 + c);
#pragma unroll
      for (int co2 = 0; co2 < 32; ++co2)
        acc[co2] = fmaf(xv, wrow[co2 * 256], acc[co2]);
    }
  }
  const int n = n0 + tid;
  float4* dst4 = (float4*)(q_t + ((size_t)b * 4096 + n) * 256 + co0);
#pragma unroll
  for (int c4 = 0; c4 < 8; ++c4) {
    float4 v;
    v.x = fmaxf(acc[4*c4+0] + bq[co0+4*c4+0], 0.f);
    v.y = fmaxf(acc[4*c4+1] + bq[co0+4*c4+1], 0.f);
    v.z = fmaxf(acc[4*c4+2] + bq[co0+4*c4+2], 0.f);
    v.w = fmaxf(acc[4*c4+3] + bq[co0+4*c4+3], 0.f);
    dst4[c4] = v;
  }
}

// ---------------- Kernel B: 3x3 conv (pad 1) + bias + relu -> k_t, v_t -----
__global__ __launch_bounds__(256) void k_conv3x3(
    const float* __restrict__ x, const float* __restrict__ wkv,
    const float* __restrict__ bkv, float* __restrict__ k_t,
    float* __restrict__ v_t)
{
  __shared__ float xs[8][18][18];  // 8 ci x (16+2)^2 halo tile
  const int tid  = threadIdx.x;
  const int tile = blockIdx.x;              // 0..15 -> 4x4 spatial tiles
  const int ty0  = (tile >> 2) * 16, tx0 = (tile & 3) * 16;
  const int co0  = blockIdx.y * 32;         // 0..480
  const int b    = blockIdx.z;
  const int iy   = tid >> 4, ix = tid & 15;

  float acc[32];
#pragma unroll
  for (int i = 0; i < 32; ++i) acc[i] = 0.f;

  const float* xb = x + (size_t)b * 256 * 4096;
  for (int ci0 = 0; ci0 < 256; ci0 += 8) {
    __syncthreads();
    for (int i = tid; i < 8 * 324; i += 256) {
      int c = i / 324, rem = i - c * 324;
      int r = rem / 18, cc = rem - r * 18;
      int gy = ty0 + r - 1, gx = tx0 + cc - 1;
      float v = 0.f;
      if ((unsigned)gy < 64u && (unsigned)gx < 64u)
        v = xb[(size_t)(ci0 + c) * 4096 + gy * 64 + gx];
      (&xs[0][0][0])[i] = v;
    }
    __syncthreads();
    for (int c = 0; c < 8; ++c) {
      float t00 = xs[c][iy+0][ix+0], t01 = xs[c][iy+0][ix+1], t02 = xs[c][iy+0][ix+2];
      float t10 = xs[c][iy+1][ix+0], t11 = xs[c][iy+1][ix+1], t12 = xs[c][iy+1][ix+2];
      float t20 = xs[c][iy+2][ix+0], t21 = xs[c][iy+2][ix+1], t22 = xs[c][iy+2][ix+2];
      const float* wb = wkv + ((size_t)co0 * 256 + (ci0 + c)) * 9;
#pragma unroll
      for (int co2 = 0; co2 < 32; ++co2) {
        const float* w = wb + (size_t)co2 * 256 * 9;
        float a = acc[co2];
        a = fmaf(t00, w[0], a); a = fmaf(t01, w[1], a); a = fmaf(t02, w[2], a);
        a = fmaf(t10, w[3], a); a = fmaf(t11, w[4], a); a = fmaf(t12, w[5], a);
        a = fmaf(t20, w[6], a); a = fmaf(t21, w[7], a); a = fmaf(t22, w[8], a);
        acc[co2] = a;
      }
    }
  }
  const int n = (ty0 + iy) * 64 + tx0 + ix;
  float* base = (co0 < 256)
      ? (k_t + ((size_t)b * 4096 + n) * 256 + co0)
      : (v_t + ((size_t)b * 4096 + n) * 256 + (co0 - 256));
  float4* dst4 = (float4*)base;
#pragma unroll
  for (int c4 = 0; c4 < 8; ++c4) {
    float4 v;
    v.x = fmaxf(acc[4*c4+0] + bkv[co0+4*c4+0], 0.f);
    v.y = fmaxf(acc[4*c4+1] + bkv[co0+4*c4+1], 0.f);
    v.z = fmaxf(acc[4*c4+2] + bkv[co0+4*c4+2], 0.f);
    v.w = fmaxf(acc[4*c4+3] + bkv[co0+4*c4+3], 0.f);
    dst4[c4] = v;
  }
}

// ---------------- Kernel C: flash attention + residual -> y (d_out, NCHW) --
// block: 256 thr = 4 waves; wave w owns 16 queries; lane owns d4 slice (4 dm)
// LDS (dynamic, 144KB): qs[64][256] | kv[64][256] (f4-swizzled) | ps[4][16][64]
__global__ __launch_bounds__(256) void k_attn(
    const float* __restrict__ q_t, const float* __restrict__ k_t,
    const float* __restrict__ v_t, const float* __restrict__ x,
    float* __restrict__ y)
{
  extern __shared__ float smem[];
  float4* qs4 = (float4*)smem;             // 64 rows x 64 float4
  float4* kv4 = (float4*)(smem + 16384);   // 64 rows x 64 float4 (swizzled)
  float*  ps  = smem + 32768;              // [4][16][64]

  const int tid  = threadIdx.x;
  const int lane = tid & 63;
  const int w    = tid >> 6;
  const int b    = blockIdx.y;
  const int q0   = blockIdx.x * 64;
  const int jswz = lane & 15;

  // stage Q once, folding the 1/sqrt(256) softmax scale
  {
    const float4* src = (const float4*)(q_t + ((size_t)b * 4096 + q0) * 256);
    for (int f = tid; f < 4096; f += 256) {
      float4 v = src[f];
      v.x *= 0.0625f; v.y *= 0.0625f; v.z *= 0.0625f; v.w *= 0.0625f;
      qs4[f] = v;
    }
  }

  float o[16][4];
#pragma unroll
  for (int i = 0; i < 16; ++i) { o[i][0]=0.f; o[i][1]=0.f; o[i][2]=0.f; o[i][3]=0.f; }
  float m[16], l[16], alpha[16];
#pragma unroll
  for (int i = 0; i < 16; ++i) { m[i] = -1e30f; l[i] = 0.f; alpha[i] = 0.f; }

  for (int t = 0; t < 64; ++t) {
    __syncthreads();  // prior PV done (and Q staging on t==0)
    {  // stage K tile (swizzled: f4 col d4 stored at d4 ^ (j&15))
      const float4* src = (const float4*)(k_t + ((size_t)b * 4096 + (size_t)t * 64) * 256);
      for (int f = tid; f < 4096; f += 256)
        kv4[(f & ~63) | ((f & 63) ^ ((f >> 6) & 15))] = src[f];
    }
    __syncthreads();

    // ---- QK^T: lane = key j, 4-query register blocking ----
#pragma unroll
    for (int g = 0; g < 4; ++g) {
      float s[4] = {0.f, 0.f, 0.f, 0.f};
      const float4* qr = qs4 + ((w << 4) + (g << 2)) * 64;
      const float4* kr = kv4 + lane * 64;
#pragma unroll 4
      for (int d4 = 0; d4 < 64; ++d4) {
        float4 kf = kr[d4 ^ jswz];
#pragma unroll
        for (int qq = 0; qq < 4; ++qq) {
          float4 qv = qr[qq * 64 + d4];
          s[qq] = fmaf(qv.x, kf.x, s[qq]);
          s[qq] = fmaf(qv.y, kf.y, s[qq]);
          s[qq] = fmaf(qv.z, kf.z, s[qq]);
          s[qq] = fmaf(qv.w, kf.w, s[qq]);
        }
      }
      // online softmax (wave-uniform m,l after butterfly reductions)
#pragma unroll
      for (int qq = 0; qq < 4; ++qq) {
        const int qi = (g << 2) + qq;
        float mx = s[qq];
#pragma unroll
        for (int sh = 32; sh; sh >>= 1) mx = fmaxf(mx, __shfl_xor(mx, sh));
        float mn = fmaxf(m[qi], mx);
        float p  = __expf(s[qq] - mn);
        float su = p;
#pragma unroll
        for (int sh = 32; sh; sh >>= 1) su += __shfl_xor(su, sh);
        float al = __expf(m[qi] - mn);
        l[qi] = fmaf(l[qi], al, su);
        m[qi] = mn;
        alpha[qi] = al;
        ps[((w << 4) + qi) * 64 + lane] = p;
      }
    }
    __syncthreads();  // all waves done with K + ps written

    {  // stage V tile into the same buffer
      const float4* src = (const float4*)(v_t + ((size_t)b * 4096 + (size_t)t * 64) * 256);
      for (int f = tid; f < 4096; f += 256)
        kv4[(f & ~63) | ((f & 63) ^ ((f >> 6) & 15))] = src[f];
    }
    __syncthreads();

    // ---- PV: lane = d4 slice, 4-key register blocking ----
#pragma unroll
    for (int qi = 0; qi < 16; ++qi) {
      float al = alpha[qi];
      o[qi][0] *= al; o[qi][1] *= al; o[qi][2] *= al; o[qi][3] *= al;
    }
    for (int j4 = 0; j4 < 64; j4 += 4) {
      float4 v0 = kv4[(j4+0) * 64 + (lane ^ ((j4+0) & 15))];
      float4 v1 = kv4[(j4+1) * 64 + (lane ^ ((j4+1) & 15))];
      float4 v2 = kv4[(j4+2) * 64 + (lane ^ ((j4+2) & 15))];
      float4 v3 = kv4[(j4+3) * 64 + (lane ^ ((j4+3) & 15))];
#pragma unroll
      for (int qi = 0; qi < 16; ++qi) {
        float4 p = *(const float4*)&ps[((w << 4) + qi) * 64 + j4];
        o[qi][0]=fmaf(p.x,v0.x,o[qi][0]); o[qi][0]=fmaf(p.y,v1.x,o[qi][0]); o[qi][0]=fmaf(p.z,v2.x,o[qi][0]); o[qi][0]=fmaf(p.w,v3.x,o[qi][0]);
        o[qi][1]=fmaf(p.x,v0.y,o[qi][1]); o[qi][1]=fmaf(p.y,v1.y,o[qi][1]); o[qi][1]=fmaf(p.z,v2.y,o[qi][1]); o[qi][1]=fmaf(p.w,v3.y,o[qi][1]);
        o[qi][2]=fmaf(p.x,v0.z,o[qi][2]); o[qi][2]=fmaf(p.y,v1.z,o[qi][2]); o[qi][2]=fmaf(p.z,v2.z,o[qi][2]); o[qi][2]=fmaf(p.w,v3.z,o[qi][2]);
        o[qi][3]=fmaf(p.x,v0.w,o[qi][3]); o[qi][3]=fmaf(p.y,v1.w,o[qi][3]); o[qi][3]=fmaf(p.z,v2.w,o[qi][3]); o[qi][3]=fmaf(p.w,v3.w,o[qi][3]);
      }
    }
  }

  // epilogue: y[b][c][n] = o/l + x[b][c][n]   (c = 4*lane + k)
  const float* xb = x + (size_t)b * 256 * 4096;
  float*       yb = y + (size_t)b * 256 * 4096;
#pragma unroll
  for (int qi = 0; qi < 16; ++qi) {
    const int n = q0 + (w << 4) + qi;
    float inv = 1.f / l[qi];
#pragma unroll
    for (int k = 0; k < 4; ++k) {
      const int c = 4 * lane + k;
      yb[(size_t)c * 4096 + n] = fmaf(o[qi][k], inv, xb[(size_t)c * 4096 + n]);
    }
  }
}

// ---------------- Kernel D: BN batch stats -> scale/shift per channel ------
__global__ __launch_bounds__(256) void k_bnstats(
    const float* __restrict__ y, const float* __restrict__ gamma,
    const float* __restrict__ beta, float* __restrict__ scale,
    float* __restrict__ shift)
{
  const int c = blockIdx.x;
  const int tid = threadIdx.x;
  double s1 = 0.0, s2 = 0.0;
  for (int i = tid; i < 32768; i += 256) {
    int bb = i >> 12, n = i & 4095;
    float v = y[((size_t)bb * 256 + c) * 4096 + n];
    s1 += (double)v;
    s2 += (double)v * (double)v;
  }
  __shared__ double r1[256], r2[256];
  r1[tid] = s1; r2[tid] = s2;
  __syncthreads();
  for (int st = 128; st; st >>= 1) {
    if (tid < st) { r1[tid] += r1[tid + st]; r2[tid] += r2[tid + st]; }
    __syncthreads();
  }
  if (tid == 0) {
    double mean = r1[0] / 32768.0;
    double var  = r2[0] / 32768.0 - mean * mean;
    double inv  = 1.0 / sqrt(var + 1e-5);
    double g = (double)gamma[c];
    scale[c] = (float)(g * inv);
    shift[c] = (float)((double)beta[c] - mean * g * inv);
  }
}

// ---------------- Kernel E: apply BN in place ------------------------------
__global__ __launch_bounds__(256) void k_bnapply(
    float* __restrict__ y, const float* __restrict__ scale,
    const float* __restrict__ shift)
{
  const int total4 = 8 * 256 * 1024;
  for (int i = blockIdx.x * 256 + threadIdx.x; i < total4; i += gridDim.x * 256) {
    int c = (i >> 10) & 255;
    float sc = scale[c], sh = shift[c];
    float4 v = ((const float4*)y)[i];
    v.x = fmaf(v.x, sc, sh);
    v.y = fmaf(v.y, sc, sh);
    v.z = fmaf(v.z, sc, sh);
    v.w = fmaf(v.w, sc, sh);
    ((float4*)y)[i] = v;
  }
}

// ---------------------------------------------------------------------------
extern "C" void kernel_launch(void* const* d_in, const int* in_sizes, int n_in,
                              void* d_out, int out_size, void* d_ws, size_t ws_size,
                              hipStream_t stream) {
  const float* x     = (const float*)d_in[0];
  const float* wq    = (const float*)d_in[1];
  const float* bq    = (const float*)d_in[2];
  const float* wkv   = (const float*)d_in[3];
  const float* bkv   = (const float*)d_in[4];
  const float* gamma = (const float*)d_in[5];
  const float* beta  = (const float*)d_in[6];
  float* out = (float*)d_out;

  const size_t TOK = (size_t)8 * 4096 * 256;
  float* q_t   = (float*)d_ws;
  float* k_t   = q_t + TOK;
  float* v_t   = k_t + TOK;
  float* scale = v_t + TOK;
  float* shift = scale + 256;

  k_conv1x1<<<dim3(16, 8, 8),  256, 0, stream>>>(x, wq, bq, q_t);
  k_conv3x3<<<dim3(16, 16, 8), 256, 0, stream>>>(x, wkv, bkv, k_t, v_t);

  const int attn_smem = 147456;  // 144 KB dynamic LDS
  hipFuncSetAttribute(reinterpret_cast<const void*>(k_attn),
                      hipFuncAttributeMaxDynamicSharedMemorySize, attn_smem);
  k_attn<<<dim3(64, 8), 256, attn_smem, stream>>>(q_t, k_t, v_t, x, out);

  k_bnstats<<<dim3(256), 256, 0, stream>>>(out, gamma, beta, scale, shift);
  k_bnapply<<<dim3(2048), 256, 0, stream>>>(out, scale, shift);
}

// Round 2
// 3309.649 us; speedup vs baseline: 2.8597x; 2.8597x over previous
//
#include <hip/hip_runtime.h>

// ---------------------------------------------------------------------------
// Sizes (fixed): B=8, C=dm=256, H=W=64, N=4096
// ws: q_t[8][4096][256] (tok-major) | k_t[8][4096][256] (tok-major) |
//     v_t[8][256][4096] (NCHW!)    | scale[256] | shift[256]
// d_out: y = r + xc (NCHW fp32), BN applied in place.
// ---------------------------------------------------------------------------

typedef __attribute__((ext_vector_type(8))) short bf16x8;
typedef __attribute__((ext_vector_type(4))) float f32x4;

__device__ inline unsigned short f2bf(float f) {
  union { float f; unsigned u; } c; c.f = f;
  unsigned u = c.u;
  return (unsigned short)((u + 0x7fffu + ((u >> 16) & 1u)) >> 16);  // RNE
}

// ---------------- Kernel A: 1x1 conv + bias + relu -> q_t [b][n][c] --------
__global__ __launch_bounds__(256) void k_conv1x1(
    const float* __restrict__ x, const float* __restrict__ wq,
    const float* __restrict__ bq, float* __restrict__ q_t)
{
  __shared__ float xs[8 * 256];
  const int tid = threadIdx.x;
  const int n0  = blockIdx.x * 256;
  const int co0 = blockIdx.y * 32;
  const int b   = blockIdx.z;

  float acc[32];
#pragma unroll
  for (int i = 0; i < 32; ++i) acc[i] = 0.f;

  const float* xb = x + (size_t)b * 256 * 4096;
  for (int ci0 = 0; ci0 < 256; ci0 += 8) {
    __syncthreads();
    for (int i = tid; i < 8 * 256; i += 256) {
      int c = i >> 8, sp = i & 255;
      xs[i] = xb[(size_t)(ci0 + c) * 4096 + n0 + sp];
    }
    __syncthreads();
#pragma unroll 2
    for (int c = 0; c < 8; ++c) {
      float xv = xs[c * 256 + tid];
      const float* wrow = wq + (size_t)co0 * 256 + (ci0 + c);
#pragma unroll
      for (int co2 = 0; co2 < 32; ++co2)
        acc[co2] = fmaf(xv, wrow[co2 * 256], acc[co2]);
    }
  }
  const int n = n0 + tid;
  float4* dst4 = (float4*)(q_t + ((size_t)b * 4096 + n) * 256 + co0);
#pragma unroll
  for (int c4 = 0; c4 < 8; ++c4) {
    float4 v;
    v.x = fmaxf(acc[4*c4+0] + bq[co0+4*c4+0], 0.f);
    v.y = fmaxf(acc[4*c4+1] + bq[co0+4*c4+1], 0.f);
    v.z = fmaxf(acc[4*c4+2] + bq[co0+4*c4+2], 0.f);
    v.w = fmaxf(acc[4*c4+3] + bq[co0+4*c4+3], 0.f);
    dst4[c4] = v;
  }
}

// ---------------- Kernel B: 3x3 conv + bias + relu -> k_t (tok), v_t (NCHW)
__global__ __launch_bounds__(256) void k_conv3x3(
    const float* __restrict__ x, const float* __restrict__ wkv,
    const float* __restrict__ bkv, float* __restrict__ k_t,
    float* __restrict__ v_t)
{
  __shared__ float xs[8][18][18];
  const int tid  = threadIdx.x;
  const int tile = blockIdx.x;
  const int ty0  = (tile >> 2) * 16, tx0 = (tile & 3) * 16;
  const int co0  = blockIdx.y * 32;
  const int b    = blockIdx.z;
  const int iy   = tid >> 4, ix = tid & 15;

  float acc[32];
#pragma unroll
  for (int i = 0; i < 32; ++i) acc[i] = 0.f;

  const float* xb = x + (size_t)b * 256 * 4096;
  for (int ci0 = 0; ci0 < 256; ci0 += 8) {
    __syncthreads();
    for (int i = tid; i < 8 * 324; i += 256) {
      int c = i / 324, rem = i - c * 324;
      int r = rem / 18, cc = rem - r * 18;
      int gy = ty0 + r - 1, gx = tx0 + cc - 1;
      float v = 0.f;
      if ((unsigned)gy < 64u && (unsigned)gx < 64u)
        v = xb[(size_t)(ci0 + c) * 4096 + gy * 64 + gx];
      (&xs[0][0][0])[i] = v;
    }
    __syncthreads();
    for (int c = 0; c < 8; ++c) {
      float t00 = xs[c][iy+0][ix+0], t01 = xs[c][iy+0][ix+1], t02 = xs[c][iy+0][ix+2];
      float t10 = xs[c][iy+1][ix+0], t11 = xs[c][iy+1][ix+1], t12 = xs[c][iy+1][ix+2];
      float t20 = xs[c][iy+2][ix+0], t21 = xs[c][iy+2][ix+1], t22 = xs[c][iy+2][ix+2];
      const float* wb = wkv + ((size_t)co0 * 256 + (ci0 + c)) * 9;
#pragma unroll
      for (int co2 = 0; co2 < 32; ++co2) {
        const float* w = wb + (size_t)co2 * 256 * 9;
        float a = acc[co2];
        a = fmaf(t00, w[0], a); a = fmaf(t01, w[1], a); a = fmaf(t02, w[2], a);
        a = fmaf(t10, w[3], a); a = fmaf(t11, w[4], a); a = fmaf(t12, w[5], a);
        a = fmaf(t20, w[6], a); a = fmaf(t21, w[7], a); a = fmaf(t22, w[8], a);
        acc[co2] = a;
      }
    }
  }
  const int n = (ty0 + iy) * 64 + tx0 + ix;
  if (co0 < 256) {  // K -> token-major [b][n][c]
    float4* dst4 = (float4*)(k_t + ((size_t)b * 4096 + n) * 256 + co0);
#pragma unroll
    for (int c4 = 0; c4 < 8; ++c4) {
      float4 v;
      v.x = fmaxf(acc[4*c4+0] + bkv[co0+4*c4+0], 0.f);
      v.y = fmaxf(acc[4*c4+1] + bkv[co0+4*c4+1], 0.f);
      v.z = fmaxf(acc[4*c4+2] + bkv[co0+4*c4+2], 0.f);
      v.w = fmaxf(acc[4*c4+3] + bkv[co0+4*c4+3], 0.f);
      dst4[c4] = v;
    }
  } else {          // V -> NCHW [b][c][n] (for transposed attention staging)
    float* vb = v_t + (size_t)b * 256 * 4096 + (size_t)(co0 - 256) * 4096 + n;
#pragma unroll
    for (int co2 = 0; co2 < 32; ++co2)
      vb[(size_t)co2 * 4096] = fmaxf(acc[co2] + bkv[co0 + co2], 0.f);
  }
}

// ---------------- Kernel C: bf16 MFMA flash attention + residual -----------
// 4 waves; wave w owns q-cols [q0+16w, +16). Swapped layout: lane owns ONE q
// (col = lane&15) for both S^T and r^T; softmax state is scalar per lane.
// LDS: klds[64][264]u16 | vlds[256][72]u16 | plds[64][72]u16 ; olds aliases.
__global__ __launch_bounds__(256, 2) void k_attn(
    const float* __restrict__ q_t, const float* __restrict__ k_t,
    const float* __restrict__ v_t, const float* __restrict__ x,
    float* __restrict__ y)
{
  extern __shared__ unsigned char smem[];
  ushort (*klds)[264] = (ushort(*)[264])smem;                    // 33792 B
  ushort (*vlds)[72]  = (ushort(*)[72])(smem + 33792);           // 36864 B
  ushort (*plds)[72]  = (ushort(*)[72])(smem + 33792 + 36864);   //  9216 B
  float  (*olds)[65]  = (float(*)[65])smem;                      // 66560 B alias

  const int tid  = threadIdx.x;
  const int lane = tid & 63;
  const int w    = tid >> 6;
  const int grp  = lane >> 4;
  const int qc   = lane & 15;
  const int b    = blockIdx.y;
  const int q0   = blockIdx.x * 64;

  // Q fragments (B-operand, resident whole kernel): qf[dc] = Q[q][dc*32+grp*8..+8]/16
  bf16x8 qf[8];
  {
    const float* qrow = q_t + ((size_t)b * 4096 + q0 + 16 * w + qc) * 256;
#pragma unroll
    for (int dc = 0; dc < 8; ++dc) {
      const float4* p = (const float4*)(qrow + dc * 32 + grp * 8);
      float4 a = p[0], c = p[1];
      bf16x8 f;
      f[0] = (short)f2bf(a.x * 0.0625f); f[1] = (short)f2bf(a.y * 0.0625f);
      f[2] = (short)f2bf(a.z * 0.0625f); f[3] = (short)f2bf(a.w * 0.0625f);
      f[4] = (short)f2bf(c.x * 0.0625f); f[5] = (short)f2bf(c.y * 0.0625f);
      f[6] = (short)f2bf(c.z * 0.0625f); f[7] = (short)f2bf(c.w * 0.0625f);
      qf[dc] = f;
    }
  }

  f32x4 o[16];
#pragma unroll
  for (int dt = 0; dt < 16; ++dt) o[dt] = f32x4{0.f, 0.f, 0.f, 0.f};
  float m_run = -1e30f, l_run = 0.f;

  const float4* kbase = (const float4*)(k_t + (size_t)b * 4096 * 256);
  const float*  vbase = v_t + (size_t)b * 256 * 4096;

  for (int t = 0; t < 64; ++t) {
    __syncthreads();  // everyone done reading klds/vlds from prev tile
    // stage K tile: [key][d] bf16, rows padded to 264
    for (int i = tid; i < 4096; i += 256) {
      float4 v = kbase[(size_t)t * 4096 + i];
      int row = i >> 6, c4 = (i & 63) << 2;
      ushort4 u; u.x = f2bf(v.x); u.y = f2bf(v.y); u.z = f2bf(v.z); u.w = f2bf(v.w);
      *(ushort4*)&klds[row][c4] = u;
    }
    // stage V^T tile: [d][key] bf16, rows padded to 72 (v_t is NCHW -> coalesced)
    for (int i = tid; i < 4096; i += 256) {
      int c = i >> 4, j4 = (i & 15) << 2;
      float4 v = *(const float4*)&vbase[(size_t)c * 4096 + t * 64 + j4];
      ushort4 u; u.x = f2bf(v.x); u.y = f2bf(v.y); u.z = f2bf(v.z); u.w = f2bf(v.w);
      *(ushort4*)&vlds[c][j4] = u;
    }
    __syncthreads();

    // ---- S^T = K * Q^T : st[kt] holds S[key = kt*16+grp*4+r][q = lane&15] ----
    f32x4 st[4];
#pragma unroll
    for (int kt = 0; kt < 4; ++kt) {
      f32x4 acc = f32x4{0.f, 0.f, 0.f, 0.f};
#pragma unroll
      for (int dc = 0; dc < 8; ++dc) {
        bf16x8 ka = *(const bf16x8*)&klds[kt * 16 + qc][dc * 32 + grp * 8];
        acc = __builtin_amdgcn_mfma_f32_16x16x32_bf16(ka, qf[dc], acc, 0, 0, 0);
      }
      st[kt] = acc;
    }

    // ---- online softmax (per-lane scalar state for its q) ----
    float pmax = st[0][0];
#pragma unroll
    for (int kt = 0; kt < 4; ++kt) {
      pmax = fmaxf(pmax, fmaxf(fmaxf(st[kt][0], st[kt][1]), fmaxf(st[kt][2], st[kt][3])));
    }
    pmax = fmaxf(pmax, __shfl_xor(pmax, 16));
    pmax = fmaxf(pmax, __shfl_xor(pmax, 32));
    float mn = fmaxf(m_run, pmax);
    float al = __expf(m_run - mn);
    m_run = mn;
    float psum = 0.f;
    ushort4 pk[4];
#pragma unroll
    for (int kt = 0; kt < 4; ++kt) {
      float p0 = __expf(st[kt][0] - mn), p1 = __expf(st[kt][1] - mn);
      float p2 = __expf(st[kt][2] - mn), p3 = __expf(st[kt][3] - mn);
      psum += (p0 + p1) + (p2 + p3);
      pk[kt].x = f2bf(p0); pk[kt].y = f2bf(p1); pk[kt].z = f2bf(p2); pk[kt].w = f2bf(p3);
    }
    psum += __shfl_xor(psum, 16);
    psum += __shfl_xor(psum, 32);
    l_run = l_run * al + psum;
#pragma unroll
    for (int dt = 0; dt < 16; ++dt) {
      o[dt][0] *= al; o[dt][1] *= al; o[dt][2] *= al; o[dt][3] *= al;
    }
    // write P^T slab (per-wave private; same-wave RAW -> lgkmcnt, no barrier)
#pragma unroll
    for (int kt = 0; kt < 4; ++kt)
      *(ushort4*)&plds[w * 16 + qc][kt * 16 + grp * 4] = pk[kt];

    // ---- r^T += V^T * P : o[dt] holds r[d = dt*16+grp*4+r][q = lane&15] ----
#pragma unroll
    for (int kc = 0; kc < 2; ++kc) {
      bf16x8 pb = *(const bf16x8*)&plds[w * 16 + qc][kc * 32 + grp * 8];
#pragma unroll
      for (int dt = 0; dt < 16; ++dt) {
        bf16x8 va = *(const bf16x8*)&vlds[dt * 16 + qc][kc * 32 + grp * 8];
        o[dt] = __builtin_amdgcn_mfma_f32_16x16x32_bf16(va, pb, o[dt], 0, 0, 0);
      }
    }
  }

  // ---- epilogue: relay r^T through LDS, coalesced NCHW store of y = r + x --
  __syncthreads();
  float inv = 1.f / l_run;
#pragma unroll
  for (int dt = 0; dt < 16; ++dt)
#pragma unroll
    for (int r = 0; r < 4; ++r)
      olds[dt * 16 + grp * 4 + r][w * 16 + qc] = o[dt][r] * inv;
  __syncthreads();

  const float* xb = x + (size_t)b * 256 * 4096;
  float*       yb = y + (size_t)b * 256 * 4096;
  for (int i = tid; i < 4096; i += 256) {
    int c = i >> 4, j4 = (i & 15) << 2;
    float4 xr = *(const float4*)&xb[(size_t)c * 4096 + q0 + j4];
    float4 rv;
    rv.x = olds[c][j4 + 0] + xr.x;
    rv.y = olds[c][j4 + 1] + xr.y;
    rv.z = olds[c][j4 + 2] + xr.z;
    rv.w = olds[c][j4 + 3] + xr.w;
    *(float4*)&yb[(size_t)c * 4096 + q0 + j4] = rv;
  }
}

// ---------------- Kernel D: BN batch stats -> scale/shift per channel ------
__global__ __launch_bounds__(256) void k_bnstats(
    const float* __restrict__ y, const float* __restrict__ gamma,
    const float* __restrict__ beta, float* __restrict__ scale,
    float* __restrict__ shift)
{
  const int c = blockIdx.x;
  const int tid = threadIdx.x;
  double s1 = 0.0, s2 = 0.0;
  for (int i = tid; i < 32768; i += 256) {
    int bb = i >> 12, n = i & 4095;
    float v = y[((size_t)bb * 256 + c) * 4096 + n];
    s1 += (double)v;
    s2 += (double)v * (double)v;
  }
  __shared__ double r1[256], r2[256];
  r1[tid] = s1; r2[tid] = s2;
  __syncthreads();
  for (int st = 128; st; st >>= 1) {
    if (tid < st) { r1[tid] += r1[tid + st]; r2[tid] += r2[tid + st]; }
    __syncthreads();
  }
  if (tid == 0) {
    double mean = r1[0] / 32768.0;
    double var  = r2[0] / 32768.0 - mean * mean;
    double inv  = 1.0 / sqrt(var + 1e-5);
    double g = (double)gamma[c];
    scale[c] = (float)(g * inv);
    shift[c] = (float)((double)beta[c] - mean * g * inv);
  }
}

// ---------------- Kernel E: apply BN in place ------------------------------
__global__ __launch_bounds__(256) void k_bnapply(
    float* __restrict__ y, const float* __restrict__ scale,
    const float* __restrict__ shift)
{
  const int total4 = 8 * 256 * 1024;
  for (int i = blockIdx.x * 256 + threadIdx.x; i < total4; i += gridDim.x * 256) {
    int c = (i >> 10) & 255;
    float sc = scale[c], sh = shift[c];
    float4 v = ((const float4*)y)[i];
    v.x = fmaf(v.x, sc, sh);
    v.y = fmaf(v.y, sc, sh);
    v.z = fmaf(v.z, sc, sh);
    v.w = fmaf(v.w, sc, sh);
    ((float4*)y)[i] = v;
  }
}

// ---------------------------------------------------------------------------
extern "C" void kernel_launch(void* const* d_in, const int* in_sizes, int n_in,
                              void* d_out, int out_size, void* d_ws, size_t ws_size,
                              hipStream_t stream) {
  const float* x     = (const float*)d_in[0];
  const float* wq    = (const float*)d_in[1];
  const float* bq    = (const float*)d_in[2];
  const float* wkv   = (const float*)d_in[3];
  const float* bkv   = (const float*)d_in[4];
  const float* gamma = (const float*)d_in[5];
  const float* beta  = (const float*)d_in[6];
  float* out = (float*)d_out;

  const size_t TOK = (size_t)8 * 4096 * 256;
  float* q_t   = (float*)d_ws;
  float* k_t   = q_t + TOK;
  float* v_t   = k_t + TOK;   // NCHW layout [b][c][n]
  float* scale = v_t + TOK;
  float* shift = scale + 256;

  k_conv1x1<<<dim3(16, 8, 8),  256, 0, stream>>>(x, wq, bq, q_t);
  k_conv3x3<<<dim3(16, 16, 8), 256, 0, stream>>>(x, wkv, bkv, k_t, v_t);

  const int attn_smem = 79872;  // klds+vlds+plds (olds aliases the front)
  hipFuncSetAttribute(reinterpret_cast<const void*>(k_attn),
                      hipFuncAttributeMaxDynamicSharedMemorySize, attn_smem);
  k_attn<<<dim3(64, 8), 256, attn_smem, stream>>>(q_t, k_t, v_t, x, out);

  k_bnstats<<<dim3(256), 256, 0, stream>>>(out, gamma, beta, scale, shift);
  k_bnapply<<<dim3(2048), 256, 0, stream>>>(out, scale, shift);
}

// Round 3
// 580.075 us; speedup vs baseline: 16.3159x; 5.7056x over previous
//
#include <hip/hip_runtime.h>

// ---------------------------------------------------------------------------
// Sizes (fixed): B=8, C=dm=256, H=W=64, N=4096
// ws (ushort units):
//   xt_pad [8][4224][256] bf16   (row 0 <-> n=-64; 64-row zero halos)
//   wt3    [9][512][256]  bf16   (k=(tap,ci), co-major rows)
//   wt1    [1][256][256]  bf16
//   q_t    [8][4096][256] bf16 token-major (1/16 scale folded)
//   k_t    [8][4096][256] bf16 token-major
//   v_t    [8][256][4096] bf16 NCHW
//   scale/shift float[256]
// d_out: y = r + xc (NCHW fp32), BN applied in place.
// ---------------------------------------------------------------------------

typedef __attribute__((ext_vector_type(8))) short bf16x8;
typedef __attribute__((ext_vector_type(4))) float f32x4;
typedef __attribute__((ext_vector_type(8))) unsigned short u16x8;

__device__ inline unsigned short f2bf(float f) {
  union { float f; unsigned u; } c; c.f = f;
  unsigned u = c.u;
  return (unsigned short)((u + 0x7fffu + ((u >> 16) & 1u)) >> 16);  // RNE
}

// ---------------- K1: transpose + cast x -> xt_pad (and zero halos) --------
__global__ __launch_bounds__(256) void k_xt(
    const float* __restrict__ x, ushort* __restrict__ xt)
{
  const int b = blockIdx.z, ci0 = blockIdx.y * 64, gx = blockIdx.x;
  const int t = threadIdx.x;
  ushort* img = xt + (size_t)b * 4224 * 256;  // row 0 == n=-64
  if (gx >= 64) {  // zero halos
    int r0 = (gx == 64) ? 0 : 4160;
#pragma unroll
    for (int k = 0; k < 2; ++k) {
      int idx = t + k * 256;          // 512 units of 8 ushorts
      int r = idx >> 3, u = idx & 7;
      u16x8 z = (u16x8)0;
      *(u16x8*)&img[(size_t)(r0 + r) * 256 + ci0 + u * 8] = z;
    }
    return;
  }
  const int n0 = gx * 64;
  __shared__ ushort tl[64][65];  // [n][ci], odd pitch to spread banks
  {
    const float* xb = x + ((size_t)b * 256 + ci0) * 4096 + n0;
    int i = t >> 2, j0 = (t & 3) * 16;
#pragma unroll
    for (int jj = 0; jj < 16; jj += 4) {
      float4 v = *(const float4*)&xb[(size_t)i * 4096 + j0 + jj];
      tl[j0 + jj + 0][i] = f2bf(v.x);
      tl[j0 + jj + 1][i] = f2bf(v.y);
      tl[j0 + jj + 2][i] = f2bf(v.z);
      tl[j0 + jj + 3][i] = f2bf(v.w);
    }
  }
  __syncthreads();
  {
    int j = t >> 3, u = t & 7;
#pragma unroll
    for (int k = 0; k < 2; ++k) {
      int jr = j + k * 32;
      ushort tmp[8];
#pragma unroll
      for (int e = 0; e < 8; ++e) tmp[e] = tl[jr][u * 8 + e];
      *(u16x8*)&img[(size_t)(64 + n0 + jr) * 256 + ci0 + u * 8] = *(u16x8*)tmp;
    }
  }
}

// ---------------- K2: weight prep: w[co][ci][taps] f32 -> wt[tap][co][ci] --
__global__ __launch_bounds__(256) void k_wprep(
    const float* __restrict__ w, ushort* __restrict__ wt, int ntaps, int nco)
{
  const int co = blockIdx.x;
  const int t = threadIdx.x;
  __shared__ float ws[2304];
  const int tot = 256 * ntaps;
  for (int i = t; i < tot; i += 256) ws[i] = w[(size_t)co * tot + i];
  __syncthreads();
  for (int tap = 0; tap < ntaps; ++tap)
    wt[((size_t)tap * nco + co) * 256 + t] = f2bf(ws[t * ntaps + tap]);
}

// ---------------- K3: implicit-GEMM conv (1x1 or 3x3) via bf16 MFMA --------
// tile: M=128 pixels x N=256 couts; 256 thr = 4 waves (2M x 2N);
// wave: M=64 x N=128 -> acc[4][8] f32x4. K loop: ci-chunk(32) x tap.
// LDS: As[258][40] (A superset rows n0-65..n0+192) | Bs[256][40]; epilogue aliases.
__global__ __launch_bounds__(256, 2) void k_conv(
    const ushort* __restrict__ xt, const ushort* __restrict__ wt,
    const float* __restrict__ bias, ushort* __restrict__ outT,
    ushort* __restrict__ outV, int ntaps, int nco, float oscale)
{
  extern __shared__ unsigned char smem[];
  ushort* As = (ushort*)smem;               // 258*40 = 10320 u (20640 B)
  ushort* Bs = (ushort*)(smem + 20640);     // 256*40 = 10240 u
  __shared__ float bias_s[256];

  const int t = threadIdx.x, lane = t & 63, wv = t >> 6;
  const int wm = wv >> 1, wn = wv & 1;
  const int qc = lane & 15, grp = lane >> 4;
  const int b = blockIdx.z, n0 = blockIdx.x * 128, co0 = blockIdx.y * 256;
  const bool nchw = (outV != nullptr) && (blockIdx.y == 1);
  const ushort* img = xt + (size_t)b * 4224 * 256 + (size_t)64 * 256;  // n=0

  bias_s[t] = bias[co0 + t];

  f32x4 acc[4][8];
#pragma unroll
  for (int mi = 0; mi < 4; ++mi)
#pragma unroll
    for (int ni = 0; ni < 8; ++ni) acc[mi][ni] = f32x4{0.f, 0.f, 0.f, 0.f};

  for (int c8 = 0; c8 < 8; ++c8) {
    const int ci0 = c8 * 32;
    __syncthreads();  // prev tap's compute done with As
    // stage A superset: rows r=0..257 <- xt[n0 + r - 65][ci0..ci0+32)
#pragma unroll
    for (int k = 0; k < 5; ++k) {
      int idx = t + k * 256;
      if (idx < 1032) {
        int r = idx >> 2, u = idx & 3;
        int n = n0 + r - 65;
        n = min(max(n, -64), 4159);
        u16x8 v = *(const u16x8*)&img[(size_t)n * 256 + ci0 + u * 8];
        *(u16x8*)&As[r * 40 + u * 8] = v;
      }
    }
    for (int tap = 0; tap < ntaps; ++tap) {
      const int dy = (ntaps == 9) ? (tap / 3 - 1) : 0;
      const int dx = (ntaps == 9) ? (tap % 3 - 1) : 0;
      const int off = dy * 64 + dx;
      __syncthreads();  // prev compute done with Bs (and As staged, tap==0)
      // stage B: 256 co x 32 ci
      const ushort* wrow = wt + ((size_t)tap * nco + co0) * 256 + ci0;
#pragma unroll
      for (int k = 0; k < 4; ++k) {
        int idx = t + k * 256;
        int r = idx >> 2, u = idx & 3;
        *(u16x8*)&Bs[r * 40 + u * 8] = *(const u16x8*)&wrow[(size_t)r * 256 + u * 8];
      }
      __syncthreads();
      // one K=32 step
      bf16x8 bf[8];
#pragma unroll
      for (int ni = 0; ni < 8; ++ni)
        bf[ni] = *(const bf16x8*)&Bs[(wn * 128 + ni * 16 + qc) * 40 + grp * 8];
#pragma unroll
      for (int mi = 0; mi < 4; ++mi) {
        int ar = wm * 64 + mi * 16 + qc + off + 65;
        bf16x8 af = *(const bf16x8*)&As[ar * 40 + grp * 8];
        if (dx < 0 && mi == 0 && qc == 0)  af = (bf16x8)0;  // w==0 edge
        if (dx > 0 && mi == 3 && qc == 15) af = (bf16x8)0;  // w==63 edge
#pragma unroll
        for (int ni = 0; ni < 8; ++ni)
          acc[mi][ni] = __builtin_amdgcn_mfma_f32_16x16x32_bf16(af, bf[ni], acc[mi][ni], 0, 0, 0);
      }
    }
  }

  __syncthreads();
  if (!nchw) {
    ushort (*olds)[264] = (ushort(*)[264])smem;  // [128 pix][256 co]
#pragma unroll
    for (int mi = 0; mi < 4; ++mi) {
      int p = wm * 64 + mi * 16 + grp * 4;
#pragma unroll
      for (int ni = 0; ni < 8; ++ni) {
        int c = wn * 128 + ni * 16 + qc;
        float bv = bias_s[c];
#pragma unroll
        for (int r = 0; r < 4; ++r)
          olds[p + r][c] = f2bf(fmaxf(acc[mi][ni][r] + bv, 0.f) * oscale);
      }
    }
    __syncthreads();
    ushort* dst = outT + ((size_t)b * 4096 + n0) * 256;
#pragma unroll
    for (int k = 0; k < 16; ++k) {
      int idx = t + k * 256;  // 4096 units
      int r = idx >> 5, u = idx & 31;
      *(u16x8*)&dst[(size_t)r * 256 + u * 8] = *(const u16x8*)&olds[r][u * 8];
    }
  } else {
    ushort (*oldsT)[136] = (ushort(*)[136])smem;  // [256 co][128 pix]
#pragma unroll
    for (int mi = 0; mi < 4; ++mi) {
      int p = wm * 64 + mi * 16 + grp * 4;
#pragma unroll
      for (int ni = 0; ni < 8; ++ni) {
        int c = wn * 128 + ni * 16 + qc;
        float bv = bias_s[c];
        ushort4 pk;
        pk.x = f2bf(fmaxf(acc[mi][ni][0] + bv, 0.f) * oscale);
        pk.y = f2bf(fmaxf(acc[mi][ni][1] + bv, 0.f) * oscale);
        pk.z = f2bf(fmaxf(acc[mi][ni][2] + bv, 0.f) * oscale);
        pk.w = f2bf(fmaxf(acc[mi][ni][3] + bv, 0.f) * oscale);
        *(ushort4*)&oldsT[c][p] = pk;
      }
    }
    __syncthreads();
    ushort* dst = outV + (size_t)b * 256 * 4096 + n0;  // channel-local
#pragma unroll
    for (int k = 0; k < 16; ++k) {
      int idx = t + k * 256;  // 4096 units
      int c = idx >> 4, u = idx & 15;
      *(u16x8*)&dst[(size_t)c * 4096 + u * 8] = *(const u16x8*)&oldsT[c][u * 8];
    }
  }
}

// ---------------- K4: bf16 MFMA flash attention + residual -----------------
__global__ __launch_bounds__(256, 2) void k_attn(
    const ushort* __restrict__ q_t, const ushort* __restrict__ k_t,
    const ushort* __restrict__ v_t, const float* __restrict__ x,
    float* __restrict__ y)
{
  extern __shared__ unsigned char smem[];
  ushort (*klds)[264] = (ushort(*)[264])smem;                    // 33792 B
  ushort (*vlds)[72]  = (ushort(*)[72])(smem + 33792);           // 36864 B
  ushort (*plds)[72]  = (ushort(*)[72])(smem + 33792 + 36864);   //  9216 B
  float  (*olds)[65]  = (float(*)[65])smem;                      // alias

  const int tid  = threadIdx.x;
  const int lane = tid & 63;
  const int w    = tid >> 6;
  const int grp  = lane >> 4;
  const int qc   = lane & 15;
  const int b    = blockIdx.y;
  const int q0   = blockIdx.x * 64;

  bf16x8 qf[8];
  {
    const ushort* qrow = q_t + ((size_t)b * 4096 + q0 + 16 * w + qc) * 256;
#pragma unroll
    for (int dc = 0; dc < 8; ++dc)
      qf[dc] = *(const bf16x8*)&qrow[dc * 32 + grp * 8];
  }

  f32x4 o[16];
#pragma unroll
  for (int dt = 0; dt < 16; ++dt) o[dt] = f32x4{0.f, 0.f, 0.f, 0.f};
  float m_run = -1e30f, l_run = 0.f;

  const ushort* kbase = k_t + (size_t)b * 4096 * 256;
  const ushort* vbase = v_t + (size_t)b * 256 * 4096;

  for (int t = 0; t < 64; ++t) {
    __syncthreads();
    // stage K tile [key][d]
    for (int i = tid; i < 2048; i += 256) {
      int row = i >> 5, c = (i & 31) * 8;
      *(u16x8*)&klds[row][c] =
          *(const u16x8*)&kbase[((size_t)t * 64 + row) * 256 + c];
    }
    // stage V^T tile [d][key] (v_t NCHW -> coalesced)
    for (int i = tid; i < 2048; i += 256) {
      int c = i >> 3, j = (i & 7) * 8;
      *(u16x8*)&vlds[c][j] =
          *(const u16x8*)&vbase[(size_t)c * 4096 + t * 64 + j];
    }
    __syncthreads();

    // S^T = K * Q^T
    f32x4 st[4];
#pragma unroll
    for (int kt = 0; kt < 4; ++kt) {
      f32x4 acc = f32x4{0.f, 0.f, 0.f, 0.f};
#pragma unroll
      for (int dc = 0; dc < 8; ++dc) {
        bf16x8 ka = *(const bf16x8*)&klds[kt * 16 + qc][dc * 32 + grp * 8];
        acc = __builtin_amdgcn_mfma_f32_16x16x32_bf16(ka, qf[dc], acc, 0, 0, 0);
      }
      st[kt] = acc;
    }

    // online softmax
    float pmax = st[0][0];
#pragma unroll
    for (int kt = 0; kt < 4; ++kt)
      pmax = fmaxf(pmax, fmaxf(fmaxf(st[kt][0], st[kt][1]), fmaxf(st[kt][2], st[kt][3])));
    pmax = fmaxf(pmax, __shfl_xor(pmax, 16));
    pmax = fmaxf(pmax, __shfl_xor(pmax, 32));
    float mn = fmaxf(m_run, pmax);
    float al = __expf(m_run - mn);
    m_run = mn;
    float psum = 0.f;
    ushort4 pk[4];
#pragma unroll
    for (int kt = 0; kt < 4; ++kt) {
      float p0 = __expf(st[kt][0] - mn), p1 = __expf(st[kt][1] - mn);
      float p2 = __expf(st[kt][2] - mn), p3 = __expf(st[kt][3] - mn);
      psum += (p0 + p1) + (p2 + p3);
      pk[kt].x = f2bf(p0); pk[kt].y = f2bf(p1); pk[kt].z = f2bf(p2); pk[kt].w = f2bf(p3);
    }
    psum += __shfl_xor(psum, 16);
    psum += __shfl_xor(psum, 32);
    l_run = l_run * al + psum;
#pragma unroll
    for (int dt = 0; dt < 16; ++dt) {
      o[dt][0] *= al; o[dt][1] *= al; o[dt][2] *= al; o[dt][3] *= al;
    }
#pragma unroll
    for (int kt = 0; kt < 4; ++kt)
      *(ushort4*)&plds[w * 16 + qc][kt * 16 + grp * 4] = pk[kt];

    // r^T += V^T * P
#pragma unroll
    for (int kc = 0; kc < 2; ++kc) {
      bf16x8 pb = *(const bf16x8*)&plds[w * 16 + qc][kc * 32 + grp * 8];
#pragma unroll
      for (int dt = 0; dt < 16; ++dt) {
        bf16x8 va = *(const bf16x8*)&vlds[dt * 16 + qc][kc * 32 + grp * 8];
        o[dt] = __builtin_amdgcn_mfma_f32_16x16x32_bf16(va, pb, o[dt], 0, 0, 0);
      }
    }
  }

  __syncthreads();
  float inv = 1.f / l_run;
#pragma unroll
  for (int dt = 0; dt < 16; ++dt)
#pragma unroll
    for (int r = 0; r < 4; ++r)
      olds[dt * 16 + grp * 4 + r][w * 16 + qc] = o[dt][r] * inv;
  __syncthreads();

  const float* xb = x + (size_t)b * 256 * 4096;
  float*       yb = y + (size_t)b * 256 * 4096;
  for (int i = tid; i < 4096; i += 256) {
    int c = i >> 4, j4 = (i & 15) << 2;
    float4 xr = *(const float4*)&xb[(size_t)c * 4096 + q0 + j4];
    float4 rv;
    rv.x = olds[c][j4 + 0] + xr.x;
    rv.y = olds[c][j4 + 1] + xr.y;
    rv.z = olds[c][j4 + 2] + xr.z;
    rv.w = olds[c][j4 + 3] + xr.w;
    *(float4*)&yb[(size_t)c * 4096 + q0 + j4] = rv;
  }
}

// ---------------- K5: BN batch stats ---------------------------------------
__global__ __launch_bounds__(256) void k_bnstats(
    const float* __restrict__ y, const float* __restrict__ gamma,
    const float* __restrict__ beta, float* __restrict__ scale,
    float* __restrict__ shift)
{
  const int c = blockIdx.x;
  const int tid = threadIdx.x;
  double s1 = 0.0, s2 = 0.0;
  for (int i = tid; i < 32768; i += 256) {
    int bb = i >> 12, n = i & 4095;
    float v = y[((size_t)bb * 256 + c) * 4096 + n];
    s1 += (double)v;
    s2 += (double)v * (double)v;
  }
  __shared__ double r1[256], r2[256];
  r1[tid] = s1; r2[tid] = s2;
  __syncthreads();
  for (int st = 128; st; st >>= 1) {
    if (tid < st) { r1[tid] += r1[tid + st]; r2[tid] += r2[tid + st]; }
    __syncthreads();
  }
  if (tid == 0) {
    double mean = r1[0] / 32768.0;
    double var  = r2[0] / 32768.0 - mean * mean;
    double inv  = 1.0 / sqrt(var + 1e-5);
    double g = (double)gamma[c];
    scale[c] = (float)(g * inv);
    shift[c] = (float)((double)beta[c] - mean * g * inv);
  }
}

// ---------------- K6: apply BN in place ------------------------------------
__global__ __launch_bounds__(256) void k_bnapply(
    float* __restrict__ y, const float* __restrict__ scale,
    const float* __restrict__ shift)
{
  const int total4 = 8 * 256 * 1024;
  for (int i = blockIdx.x * 256 + threadIdx.x; i < total4; i += gridDim.x * 256) {
    int c = (i >> 10) & 255;
    float sc = scale[c], sh = shift[c];
    float4 v = ((const float4*)y)[i];
    v.x = fmaf(v.x, sc, sh);
    v.y = fmaf(v.y, sc, sh);
    v.z = fmaf(v.z, sc, sh);
    v.w = fmaf(v.w, sc, sh);
    ((float4*)y)[i] = v;
  }
}

// ---------------------------------------------------------------------------
extern "C" void kernel_launch(void* const* d_in, const int* in_sizes, int n_in,
                              void* d_out, int out_size, void* d_ws, size_t ws_size,
                              hipStream_t stream) {
  const float* x     = (const float*)d_in[0];
  const float* wq    = (const float*)d_in[1];
  const float* bq    = (const float*)d_in[2];
  const float* wkv   = (const float*)d_in[3];
  const float* bkv   = (const float*)d_in[4];
  const float* gamma = (const float*)d_in[5];
  const float* beta  = (const float*)d_in[6];
  float* out = (float*)d_out;

  ushort* xt  = (ushort*)d_ws;            // 8*4224*256 = 8650752
  ushort* wt3 = xt  + (size_t)8650752;    // 9*512*256 = 1179648
  ushort* wt1 = wt3 + (size_t)1179648;    // 256*256   = 65536
  ushort* q_t = wt1 + (size_t)65536;      // 8388608
  ushort* k_t = q_t + (size_t)8388608;
  ushort* v_t = k_t + (size_t)8388608;
  float* scale = (float*)(v_t + (size_t)8388608);
  float* shift = scale + 256;

  k_xt<<<dim3(66, 4, 8), 256, 0, stream>>>(x, xt);
  k_wprep<<<dim3(512), 256, 0, stream>>>(wkv, wt3, 9, 512);
  k_wprep<<<dim3(256), 256, 0, stream>>>(wq, wt1, 1, 256);

  const int conv_smem = 69632;
  hipFuncSetAttribute(reinterpret_cast<const void*>(k_conv),
                      hipFuncAttributeMaxDynamicSharedMemorySize, conv_smem);
  // q = relu(conv1x1)*1/16 -> token-major
  k_conv<<<dim3(32, 1, 8), 256, conv_smem, stream>>>(
      xt, wt1, bq, q_t, nullptr, 1, 256, 0.0625f);
  // k (couts 0..255) token-major; v (couts 256..511) NCHW
  k_conv<<<dim3(32, 2, 8), 256, conv_smem, stream>>>(
      xt, wt3, bkv, k_t, v_t, 9, 512, 1.0f);

  const int attn_smem = 79872;
  hipFuncSetAttribute(reinterpret_cast<const void*>(k_attn),
                      hipFuncAttributeMaxDynamicSharedMemorySize, attn_smem);
  k_attn<<<dim3(64, 8), 256, attn_smem, stream>>>(q_t, k_t, v_t, x, out);

  k_bnstats<<<dim3(256), 256, 0, stream>>>(out, gamma, beta, scale, shift);
  k_bnapply<<<dim3(2048), 256, 0, stream>>>(out, scale, shift);
}

// Round 4
// 402.321 us; speedup vs baseline: 23.5247x; 1.4418x over previous
//
#include <hip/hip_runtime.h>

// ---------------------------------------------------------------------------
// Sizes (fixed): B=8, C=dm=256, H=W=64, N=4096
// ws (ushort units):
//   xt_pad [8][4224][256] bf16   (row 0 <-> n=-64; 64-row zero halos)
//   wt3    [9][512][256]  bf16   (k=(tap,ci), co-major rows)
//   wt1    [1][256][256]  bf16
//   q_t    [8][4096][256] bf16 token-major (1/16 scale folded)
//   k_t    [8][4096][256] bf16 token-major
//   v_t    [8][256][4096] bf16 NCHW
//   scale/shift float[256]
// d_out: y = r + xc (NCHW fp32), BN applied in place.
// ---------------------------------------------------------------------------

typedef __attribute__((ext_vector_type(8))) short bf16x8;
typedef __attribute__((ext_vector_type(4))) float f32x4;
typedef __attribute__((ext_vector_type(8))) unsigned short u16x8;

__device__ inline unsigned short f2bf(float f) {
  union { float f; unsigned u; } c; c.f = f;
  unsigned u = c.u;
  return (unsigned short)((u + 0x7fffu + ((u >> 16) & 1u)) >> 16);  // RNE
}

// async global->LDS DMA, 16 B per lane; dest = wave-uniform base + lane*16
__device__ inline void dma16(const void* g, void* l) {
  __builtin_amdgcn_global_load_lds(
      (const __attribute__((address_space(1))) unsigned int*)g,
      (__attribute__((address_space(3))) unsigned int*)l, 16, 0, 0);
}

// ---------------- K1: transpose + cast x -> xt_pad (and zero halos) --------
__global__ __launch_bounds__(256) void k_xt(
    const float* __restrict__ x, ushort* __restrict__ xt)
{
  const int b = blockIdx.z, ci0 = blockIdx.y * 64, gx = blockIdx.x;
  const int t = threadIdx.x;
  ushort* img = xt + (size_t)b * 4224 * 256;  // row 0 == n=-64
  if (gx >= 64) {  // zero halos
    int r0 = (gx == 64) ? 0 : 4160;
#pragma unroll
    for (int k = 0; k < 2; ++k) {
      int idx = t + k * 256;          // 512 units of 8 ushorts
      int r = idx >> 3, u = idx & 7;
      u16x8 z = (u16x8)0;
      *(u16x8*)&img[(size_t)(r0 + r) * 256 + ci0 + u * 8] = z;
    }
    return;
  }
  const int n0 = gx * 64;
  __shared__ ushort tl[64][65];  // [n][ci], odd pitch to spread banks
  {
    const float* xb = x + ((size_t)b * 256 + ci0) * 4096 + n0;
    int i = t >> 2, j0 = (t & 3) * 16;
#pragma unroll
    for (int jj = 0; jj < 16; jj += 4) {
      float4 v = *(const float4*)&xb[(size_t)i * 4096 + j0 + jj];
      tl[j0 + jj + 0][i] = f2bf(v.x);
      tl[j0 + jj + 1][i] = f2bf(v.y);
      tl[j0 + jj + 2][i] = f2bf(v.z);
      tl[j0 + jj + 3][i] = f2bf(v.w);
    }
  }
  __syncthreads();
  {
    int j = t >> 3, u = t & 7;
#pragma unroll
    for (int k = 0; k < 2; ++k) {
      int jr = j + k * 32;
      ushort tmp[8];
#pragma unroll
      for (int e = 0; e < 8; ++e) tmp[e] = tl[jr][u * 8 + e];
      *(u16x8*)&img[(size_t)(64 + n0 + jr) * 256 + ci0 + u * 8] = *(u16x8*)tmp;
    }
  }
}

// ---------------- K2: weight prep: w[co][ci][taps] f32 -> wt[tap][co][ci] --
__global__ __launch_bounds__(256) void k_wprep(
    const float* __restrict__ w, ushort* __restrict__ wt, int ntaps, int nco)
{
  const int co = blockIdx.x;
  const int t = threadIdx.x;
  __shared__ float ws[2304];
  const int tot = 256 * ntaps;
  for (int i = t; i < tot; i += 256) ws[i] = w[(size_t)co * tot + i];
  __syncthreads();
  for (int tap = 0; tap < ntaps; ++tap)
    wt[((size_t)tap * nco + co) * 256 + t] = f2bf(ws[t * ntaps + tap]);
}

// ---------------- K3: implicit-GEMM conv (1x1 or 3x3) via bf16 MFMA --------
__global__ __launch_bounds__(256, 2) void k_conv(
    const ushort* __restrict__ xt, const ushort* __restrict__ wt,
    const float* __restrict__ bias, ushort* __restrict__ outT,
    ushort* __restrict__ outV, int ntaps, int nco, float oscale)
{
  extern __shared__ unsigned char smem[];
  ushort* As = (ushort*)smem;               // 258*40 = 10320 u (20640 B)
  ushort* Bs = (ushort*)(smem + 20640);     // 256*40 = 10240 u
  __shared__ float bias_s[256];

  const int t = threadIdx.x, lane = t & 63, wv = t >> 6;
  const int wm = wv >> 1, wn = wv & 1;
  const int qc = lane & 15, grp = lane >> 4;
  const int b = blockIdx.z, n0 = blockIdx.x * 128, co0 = blockIdx.y * 256;
  const bool nchw = (outV != nullptr) && (blockIdx.y == 1);
  const ushort* img = xt + (size_t)b * 4224 * 256 + (size_t)64 * 256;  // n=0

  bias_s[t] = bias[co0 + t];

  f32x4 acc[4][8];
#pragma unroll
  for (int mi = 0; mi < 4; ++mi)
#pragma unroll
    for (int ni = 0; ni < 8; ++ni) acc[mi][ni] = f32x4{0.f, 0.f, 0.f, 0.f};

  for (int c8 = 0; c8 < 8; ++c8) {
    const int ci0 = c8 * 32;
    __syncthreads();  // prev tap's compute done with As
#pragma unroll
    for (int k = 0; k < 5; ++k) {
      int idx = t + k * 256;
      if (idx < 1032) {
        int r = idx >> 2, u = idx & 3;
        int n = n0 + r - 65;
        n = min(max(n, -64), 4159);
        u16x8 v = *(const u16x8*)&img[(size_t)n * 256 + ci0 + u * 8];
        *(u16x8*)&As[r * 40 + u * 8] = v;
      }
    }
    for (int tap = 0; tap < ntaps; ++tap) {
      const int dy = (ntaps == 9) ? (tap / 3 - 1) : 0;
      const int dx = (ntaps == 9) ? (tap % 3 - 1) : 0;
      const int off = dy * 64 + dx;
      __syncthreads();  // prev compute done with Bs (and As staged, tap==0)
      const ushort* wrow = wt + ((size_t)tap * nco + co0) * 256 + ci0;
#pragma unroll
      for (int k = 0; k < 4; ++k) {
        int idx = t + k * 256;
        int r = idx >> 2, u = idx & 3;
        *(u16x8*)&Bs[r * 40 + u * 8] = *(const u16x8*)&wrow[(size_t)r * 256 + u * 8];
      }
      __syncthreads();
      bf16x8 bf[8];
#pragma unroll
      for (int ni = 0; ni < 8; ++ni)
        bf[ni] = *(const bf16x8*)&Bs[(wn * 128 + ni * 16 + qc) * 40 + grp * 8];
#pragma unroll
      for (int mi = 0; mi < 4; ++mi) {
        int ar = wm * 64 + mi * 16 + qc + off + 65;
        bf16x8 af = *(const bf16x8*)&As[ar * 40 + grp * 8];
        if (dx < 0 && mi == 0 && qc == 0)  af = (bf16x8)0;  // w==0 edge
        if (dx > 0 && mi == 3 && qc == 15) af = (bf16x8)0;  // w==63 edge
#pragma unroll
        for (int ni = 0; ni < 8; ++ni)
          acc[mi][ni] = __builtin_amdgcn_mfma_f32_16x16x32_bf16(af, bf[ni], acc[mi][ni], 0, 0, 0);
      }
    }
  }

  __syncthreads();
  if (!nchw) {
    ushort (*olds)[264] = (ushort(*)[264])smem;  // [128 pix][256 co]
#pragma unroll
    for (int mi = 0; mi < 4; ++mi) {
      int p = wm * 64 + mi * 16 + grp * 4;
#pragma unroll
      for (int ni = 0; ni < 8; ++ni) {
        int c = wn * 128 + ni * 16 + qc;
        float bv = bias_s[c];
#pragma unroll
        for (int r = 0; r < 4; ++r)
          olds[p + r][c] = f2bf(fmaxf(acc[mi][ni][r] + bv, 0.f) * oscale);
      }
    }
    __syncthreads();
    ushort* dst = outT + ((size_t)b * 4096 + n0) * 256;
#pragma unroll
    for (int k = 0; k < 16; ++k) {
      int idx = t + k * 256;
      int r = idx >> 5, u = idx & 31;
      *(u16x8*)&dst[(size_t)r * 256 + u * 8] = *(const u16x8*)&olds[r][u * 8];
    }
  } else {
    ushort (*oldsT)[136] = (ushort(*)[136])smem;  // [256 co][128 pix]
#pragma unroll
    for (int mi = 0; mi < 4; ++mi) {
      int p = wm * 64 + mi * 16 + grp * 4;
#pragma unroll
      for (int ni = 0; ni < 8; ++ni) {
        int c = wn * 128 + ni * 16 + qc;
        float bv = bias_s[c];
        ushort4 pk;
        pk.x = f2bf(fmaxf(acc[mi][ni][0] + bv, 0.f) * oscale);
        pk.y = f2bf(fmaxf(acc[mi][ni][1] + bv, 0.f) * oscale);
        pk.z = f2bf(fmaxf(acc[mi][ni][2] + bv, 0.f) * oscale);
        pk.w = f2bf(fmaxf(acc[mi][ni][3] + bv, 0.f) * oscale);
        *(ushort4*)&oldsT[c][p] = pk;
      }
    }
    __syncthreads();
    ushort* dst = outV + (size_t)b * 256 * 4096 + n0;
#pragma unroll
    for (int k = 0; k < 16; ++k) {
      int idx = t + k * 256;
      int c = idx >> 4, u = idx & 15;
      *(u16x8*)&dst[(size_t)c * 4096 + u * 8] = *(const u16x8*)&oldsT[c][u * 8];
    }
  }
}

// ---------------- K4: bf16 MFMA flash attention + residual -----------------
// 4 waves x 32 q each (two 16-q tiles sharing every K/V LDS read).
// QBLK=128 -> grid 32x8 = 256 blocks = 1/CU. Double-buffered global_load_lds
// DMA staging (pre-swizzled source), ONE barrier per KV tile. XOR granule
// swizzle (slot = g ^ (row&7)) on K/V/P rows kills bank conflicts.
// LDS: kbuf[2][64][256] | vbuf[2][256][64] | plds[128][64]  = 144 KB.
__global__ __launch_bounds__(256, 1) void k_attn(
    const ushort* __restrict__ q_t, const ushort* __restrict__ k_t,
    const ushort* __restrict__ v_t, const float* __restrict__ x,
    float* __restrict__ y)
{
  extern __shared__ unsigned char smem[];
  ushort* kbuf0 = (ushort*)smem;                    // [64][256]
  ushort* kbuf1 = (ushort*)(smem + 32768);
  ushort* vbuf0 = (ushort*)(smem + 65536);          // [256][64]
  ushort* vbuf1 = (ushort*)(smem + 98304);
  ushort* plds  = (ushort*)(smem + 131072);         // [128][64]

  const int tid = threadIdx.x, lane = tid & 63, w = tid >> 6;
  const int grp = lane >> 4, qc = lane & 15, xr3 = qc & 7;
  const int b = blockIdx.y, q0 = blockIdx.x * 128;

  const ushort* kbase = k_t + (size_t)b * 4096 * 256;
  const ushort* vbase = v_t + (size_t)b * 256 * 4096;

  // Q fragments for both 16-q tiles (1/16 scale pre-folded in q_t)
  bf16x8 qf[2][8];
#pragma unroll
  for (int u = 0; u < 2; ++u) {
    const ushort* qrow = q_t + ((size_t)b * 4096 + q0 + w * 32 + u * 16 + qc) * 256;
#pragma unroll
    for (int dc = 0; dc < 8; ++dc)
      qf[u][dc] = *(const bf16x8*)&qrow[dc * 32 + grp * 8];
  }

  f32x4 o0[16], o1[16];
#pragma unroll
  for (int dt = 0; dt < 16; ++dt) {
    o0[dt] = f32x4{0.f, 0.f, 0.f, 0.f};
    o1[dt] = f32x4{0.f, 0.f, 0.f, 0.f};
  }
  float m0 = -1e30f, l0 = 0.f, m1 = -1e30f, l1 = 0.f;

  const int wbase = (tid & ~63);  // w*64

  auto stage = [&](int t, ushort* kb, ushort* vb) {
#pragma unroll
    for (int k = 0; k < 8; ++k) {   // K tile: 2048 granules of 16B
      int i = k * 256 + tid;
      int j = i >> 5, s = i & 31;
      dma16(kbase + ((size_t)(t * 64 + j) * 256) + ((s ^ (j & 7)) << 3),
            kb + (size_t)(k * 256 + wbase) * 8);
    }
#pragma unroll
    for (int k = 0; k < 8; ++k) {   // V tile: [d][key]
      int i = k * 256 + tid;
      int c = i >> 3, s = i & 7;
      dma16(vbase + (size_t)c * 4096 + t * 64 + ((s ^ (c & 7)) << 3),
            vb + (size_t)(k * 256 + wbase) * 8);
    }
  };

  stage(0, kbuf0, vbuf0);
  asm volatile("s_waitcnt vmcnt(0)" ::: "memory");
  __syncthreads();

  ushort* prowA = plds + (size_t)(w * 32 + qc) * 64;
  ushort* prowB = prowA + 16 * 64;

  for (int t = 0; t < 64; ++t) {
    ushort* kb = (t & 1) ? kbuf1 : kbuf0;
    ushort* vb = (t & 1) ? vbuf1 : vbuf0;
    if (t < 63) stage(t + 1, (t & 1) ? kbuf0 : kbuf1, (t & 1) ? vbuf0 : vbuf1);

    // ---- S^T = K * Q^T for both q-tiles (shared ka reads) ----
    f32x4 stA[4], stB[4];
#pragma unroll
    for (int kt = 0; kt < 4; ++kt) {
      f32x4 a = f32x4{0.f, 0.f, 0.f, 0.f};
      f32x4 c = f32x4{0.f, 0.f, 0.f, 0.f};
      const int row = kt * 16 + qc;
#pragma unroll
      for (int dc = 0; dc < 8; ++dc) {
        bf16x8 ka = *(const bf16x8*)&kb[row * 256 + (((dc * 4 + grp) ^ xr3) << 3)];
        a = __builtin_amdgcn_mfma_f32_16x16x32_bf16(ka, qf[0][dc], a, 0, 0, 0);
        c = __builtin_amdgcn_mfma_f32_16x16x32_bf16(ka, qf[1][dc], c, 0, 0, 0);
      }
      stA[kt] = a; stB[kt] = c;
    }

    // ---- online softmax (defer-max THR=8), tile A ----
    {
      float pmax = stA[0][0];
#pragma unroll
      for (int kt = 0; kt < 4; ++kt)
        pmax = fmaxf(pmax, fmaxf(fmaxf(stA[kt][0], stA[kt][1]), fmaxf(stA[kt][2], stA[kt][3])));
      pmax = fmaxf(pmax, __shfl_xor(pmax, 16));
      pmax = fmaxf(pmax, __shfl_xor(pmax, 32));
      if (!__all(pmax - m0 <= 8.f)) {
        float mn = fmaxf(m0, pmax);
        float al = __expf(m0 - mn);
        m0 = mn; l0 *= al;
#pragma unroll
        for (int dt = 0; dt < 16; ++dt) {
          o0[dt][0] *= al; o0[dt][1] *= al; o0[dt][2] *= al; o0[dt][3] *= al;
        }
      }
      float psum = 0.f;
#pragma unroll
      for (int kt = 0; kt < 4; ++kt) {
        float p0 = __expf(stA[kt][0] - m0), p1 = __expf(stA[kt][1] - m0);
        float p2 = __expf(stA[kt][2] - m0), p3 = __expf(stA[kt][3] - m0);
        psum += (p0 + p1) + (p2 + p3);
        ushort4 pk; pk.x = f2bf(p0); pk.y = f2bf(p1); pk.z = f2bf(p2); pk.w = f2bf(p3);
        *(ushort4*)&prowA[(((2 * kt + (grp >> 1)) ^ xr3) << 3) + ((grp & 1) << 2)] = pk;
      }
      psum += __shfl_xor(psum, 16);
      psum += __shfl_xor(psum, 32);
      l0 += psum;
    }
    // ---- tile B ----
    {
      float pmax = stB[0][0];
#pragma unroll
      for (int kt = 0; kt < 4; ++kt)
        pmax = fmaxf(pmax, fmaxf(fmaxf(stB[kt][0], stB[kt][1]), fmaxf(stB[kt][2], stB[kt][3])));
      pmax = fmaxf(pmax, __shfl_xor(pmax, 16));
      pmax = fmaxf(pmax, __shfl_xor(pmax, 32));
      if (!__all(pmax - m1 <= 8.f)) {
        float mn = fmaxf(m1, pmax);
        float al = __expf(m1 - mn);
        m1 = mn; l1 *= al;
#pragma unroll
        for (int dt = 0; dt < 16; ++dt) {
          o1[dt][0] *= al; o1[dt][1] *= al; o1[dt][2] *= al; o1[dt][3] *= al;
        }
      }
      float psum = 0.f;
#pragma unroll
      for (int kt = 0; kt < 4; ++kt) {
        float p0 = __expf(stB[kt][0] - m1), p1 = __expf(stB[kt][1] - m1);
        float p2 = __expf(stB[kt][2] - m1), p3 = __expf(stB[kt][3] - m1);
        psum += (p0 + p1) + (p2 + p3);
        ushort4 pk; pk.x = f2bf(p0); pk.y = f2bf(p1); pk.z = f2bf(p2); pk.w = f2bf(p3);
        *(ushort4*)&prowB[(((2 * kt + (grp >> 1)) ^ xr3) << 3) + ((grp & 1) << 2)] = pk;
      }
      psum += __shfl_xor(psum, 16);
      psum += __shfl_xor(psum, 32);
      l1 += psum;
    }

    // ---- r^T += V^T * P for both q-tiles (shared va reads) ----
#pragma unroll
    for (int kc = 0; kc < 2; ++kc) {
      const int pslot = ((kc * 4 + grp) ^ xr3) << 3;
      bf16x8 pA = *(const bf16x8*)&prowA[pslot];
      bf16x8 pB = *(const bf16x8*)&prowB[pslot];
#pragma unroll
      for (int dt = 0; dt < 16; ++dt) {
        bf16x8 va = *(const bf16x8*)&vb[(dt * 16 + qc) * 64 + pslot];
        o0[dt] = __builtin_amdgcn_mfma_f32_16x16x32_bf16(va, pA, o0[dt], 0, 0, 0);
        o1[dt] = __builtin_amdgcn_mfma_f32_16x16x32_bf16(va, pB, o1[dt], 0, 0, 0);
      }
    }

    asm volatile("s_waitcnt vmcnt(0)" ::: "memory");
    __syncthreads();  // next tile's DMA landed; buffers swappable
  }

  // ---- epilogue: relay r^T via LDS, coalesced NCHW store of y = r + x ----
  float inv0 = 1.f / l0, inv1 = 1.f / l1;
  float (*olds)[132] = (float(*)[132])smem;  // [256 d][128 q + pad]
#pragma unroll
  for (int dt = 0; dt < 16; ++dt)
#pragma unroll
    for (int r = 0; r < 4; ++r) {
      olds[dt * 16 + grp * 4 + r][w * 32 + qc]      = o0[dt][r] * inv0;
      olds[dt * 16 + grp * 4 + r][w * 32 + 16 + qc] = o1[dt][r] * inv1;
    }
  __syncthreads();

  const float* xb = x + (size_t)b * 256 * 4096 + q0;
  float*       yb = y + (size_t)b * 256 * 4096 + q0;
  for (int i = tid; i < 8192; i += 256) {
    int c = i >> 5, f4 = (i & 31) << 2;
    float4 xr = *(const float4*)&xb[(size_t)c * 4096 + f4];
    float4 rv = *(const float4*)&olds[c][f4];
    rv.x += xr.x; rv.y += xr.y; rv.z += xr.z; rv.w += xr.w;
    *(float4*)&yb[(size_t)c * 4096 + f4] = rv;
  }
}

// ---------------- K5: BN batch stats ---------------------------------------
__global__ __launch_bounds__(256) void k_bnstats(
    const float* __restrict__ y, const float* __restrict__ gamma,
    const float* __restrict__ beta, float* __restrict__ scale,
    float* __restrict__ shift)
{
  const int c = blockIdx.x;
  const int tid = threadIdx.x;
  double s1 = 0.0, s2 = 0.0;
  for (int i = tid; i < 32768; i += 256) {
    int bb = i >> 12, n = i & 4095;
    float v = y[((size_t)bb * 256 + c) * 4096 + n];
    s1 += (double)v;
    s2 += (double)v * (double)v;
  }
  __shared__ double r1[256], r2[256];
  r1[tid] = s1; r2[tid] = s2;
  __syncthreads();
  for (int st = 128; st; st >>= 1) {
    if (tid < st) { r1[tid] += r1[tid + st]; r2[tid] += r2[tid + st]; }
    __syncthreads();
  }
  if (tid == 0) {
    double mean = r1[0] / 32768.0;
    double var  = r2[0] / 32768.0 - mean * mean;
    double inv  = 1.0 / sqrt(var + 1e-5);
    double g = (double)gamma[c];
    scale[c] = (float)(g * inv);
    shift[c] = (float)((double)beta[c] - mean * g * inv);
  }
}

// ---------------- K6: apply BN in place ------------------------------------
__global__ __launch_bounds__(256) void k_bnapply(
    float* __restrict__ y, const float* __restrict__ scale,
    const float* __restrict__ shift)
{
  const int total4 = 8 * 256 * 1024;
  for (int i = blockIdx.x * 256 + threadIdx.x; i < total4; i += gridDim.x * 256) {
    int c = (i >> 10) & 255;
    float sc = scale[c], sh = shift[c];
    float4 v = ((const float4*)y)[i];
    v.x = fmaf(v.x, sc, sh);
    v.y = fmaf(v.y, sc, sh);
    v.z = fmaf(v.z, sc, sh);
    v.w = fmaf(v.w, sc, sh);
    ((float4*)y)[i] = v;
  }
}

// ---------------------------------------------------------------------------
extern "C" void kernel_launch(void* const* d_in, const int* in_sizes, int n_in,
                              void* d_out, int out_size, void* d_ws, size_t ws_size,
                              hipStream_t stream) {
  const float* x     = (const float*)d_in[0];
  const float* wq    = (const float*)d_in[1];
  const float* bq    = (const float*)d_in[2];
  const float* wkv   = (const float*)d_in[3];
  const float* bkv   = (const float*)d_in[4];
  const float* gamma = (const float*)d_in[5];
  const float* beta  = (const float*)d_in[6];
  float* out = (float*)d_out;

  ushort* xt  = (ushort*)d_ws;            // 8*4224*256 = 8650752
  ushort* wt3 = xt  + (size_t)8650752;    // 9*512*256 = 1179648
  ushort* wt1 = wt3 + (size_t)1179648;    // 256*256   = 65536
  ushort* q_t = wt1 + (size_t)65536;      // 8388608
  ushort* k_t = q_t + (size_t)8388608;
  ushort* v_t = k_t + (size_t)8388608;
  float* scale = (float*)(v_t + (size_t)8388608);
  float* shift = scale + 256;

  k_xt<<<dim3(66, 4, 8), 256, 0, stream>>>(x, xt);
  k_wprep<<<dim3(512), 256, 0, stream>>>(wkv, wt3, 9, 512);
  k_wprep<<<dim3(256), 256, 0, stream>>>(wq, wt1, 1, 256);

  const int conv_smem = 69632;
  hipFuncSetAttribute(reinterpret_cast<const void*>(k_conv),
                      hipFuncAttributeMaxDynamicSharedMemorySize, conv_smem);
  k_conv<<<dim3(32, 1, 8), 256, conv_smem, stream>>>(
      xt, wt1, bq, q_t, nullptr, 1, 256, 0.0625f);
  k_conv<<<dim3(32, 2, 8), 256, conv_smem, stream>>>(
      xt, wt3, bkv, k_t, v_t, 9, 512, 1.0f);

  const int attn_smem = 147456;  // 144 KB
  hipFuncSetAttribute(reinterpret_cast<const void*>(k_attn),
                      hipFuncAttributeMaxDynamicSharedMemorySize, attn_smem);
  k_attn<<<dim3(32, 8), 256, attn_smem, stream>>>(q_t, k_t, v_t, x, out);

  k_bnstats<<<dim3(256), 256, 0, stream>>>(out, gamma, beta, scale, shift);
  k_bnapply<<<dim3(2048), 256, 0, stream>>>(out, scale, shift);
}